// Round 2
// baseline (719.502 us; speedup 1.0000x reference)
//
#include <hip/hip_runtime.h>
#include <math.h>

#define B_  128
#define P_  2048
#define NB_ 2000
#define NF_ 250
#define NC_ 16
#define R_  128
#define LS_ 1750   // NB-NF (len_sim)
#define NT_ 1751   // NB-NF+1
#define BR_ (B_ * R_)
#define H_  16     // steps per block
#define NBLK_ 110  // number of 16-step blocks covering LS_ (t0 = 0..1744)

typedef int v4i __attribute__((ext_vector_type(4)));

// ---- DPP quad-perm on 64-bit (2x mov_dpp b32) ----
template <int CTRL>
__device__ __forceinline__ long long dpp64i(long long x) {
    int lo = (int)x, hi = (int)(x >> 32);
    lo = __builtin_amdgcn_mov_dpp(lo, CTRL, 0xF, 0xF, true);
    hi = __builtin_amdgcn_mov_dpp(hi, CTRL, 0xF, 0xF, true);
    return ((long long)(unsigned)lo) | ((long long)hi << 32);
}
// quad bcast lane g: CTRL = 0x55 * g

// ---- custom logit: log(u/(1-u)) f64, abs err < 1e-13 (margin ~2e-7) ----
__device__ __forceinline__ double logit_fast(float uf) {
    double u = (double)uf;
    double v = 1.0 - u;                  // exact (u has 24-bit mantissa)
    double qd = u / v;
    long long bits = __double_as_longlong(qd);
    int e = (int)((bits >> 52) & 0x7FF) - 1023;
    double m = __longlong_as_double((bits & 0xFFFFFFFFFFFFFLL) | 0x3FF0000000000000LL);
    if (m > 1.4142135623730951) { m *= 0.5; e += 1; }   // m in [0.707,1.414]
    double s = (m - 1.0) / (m + 1.0);                   // |s| <= 0.1716
    double z = s * s;
    double Q = fma(z, fma(z, fma(z, fma(z, fma(z, fma(z,
        0.06666666666666667, 0.07692307692307693), 0.09090909090909091),
        0.1111111111111111), 0.14285714285714285), 0.2), 0.3333333333333333);
    double logm = fma(2.0 * s, z * Q, 2.0 * s);         // 2*atanh(s)
    return fma((double)e, 0.6931471805599453, logm);
}

// ---- clamp + quantize threshold to i64 at 2^45 (|ns| < 8 guaranteed) ----
__device__ __forceinline__ long long thrq_of(double lu, double fb) {
    double thr = lu - fb;
    thr = fmin(fmax(thr, -8.0), 8.0);
    double d = fma(thr, 0x1p45, 0x1.8p52);              // + (2^52 + 2^51)
    return (__double_as_longlong(d) & 0xFFFFFFFFFFFFFLL) - (1LL << 51);
}

// ---------------- fused: ft (blocks 0..6) + sdot (blocks 7..134) ----------------
__global__ __launch_bounds__(256) void k_pre(const float* __restrict__ st,
                                             const float* __restrict__ stf,
                                             const float* __restrict__ sp,
                                             const float* __restrict__ sf,
                                             double* __restrict__ ft,
                                             double* __restrict__ sdot) {
    if (blockIdx.x < 7) {
        int t = blockIdx.x * 256 + threadIdx.x;
        if (t >= NT_) return;
        double s = 0.0;
        for (int k = 0; k < NF_; ++k) s += (double)st[t + k] * (double)stf[k];
        ft[t] = s;
    } else {
        __shared__ double red[256];
        int b = blockIdx.x - 7;
        double s = 0.0;
        for (int p = threadIdx.x; p < P_; p += 256)
            s += (double)sp[(size_t)b * P_ + p] * (double)sf[p];
        red[threadIdx.x] = s;
        __syncthreads();
        for (int off = 128; off > 0; off >>= 1) {
            if (threadIdx.x < off) red[threadIdx.x] += red[threadIdx.x + off];
            __syncthreads();
        }
        if (threadIdx.x == 0) sdot[b] = red[0];
    }
}

// ---------------- gensig[b,t] = sdot[b]*ft[t] + bias + coup[b,t], f64 ----------------
__global__ __launch_bounds__(256) void k_coup(const float* __restrict__ cc,
                                              const float* __restrict__ cf,
                                              const double* __restrict__ sdot,
                                              const double* __restrict__ ft,
                                              const float* __restrict__ bias,
                                              double* __restrict__ gensig) {
    __shared__ __align__(16) float  ccs[NC_ * 512];   // 32 KB
    __shared__ __align__(16) double cfs[NC_ * 256];   // 32 KB
    __shared__ double red[3][64][4];                  // 6 KB
    int b = blockIdx.y, t0 = blockIdx.x * 256;
    int tid = threadIdx.x, lane = tid & 63, wv = tid >> 6;

    for (int idx = tid; idx < NC_ * 128; idx += 256) {
        int c = idx >> 7, j4 = (idx & 127) * 4, src = t0 + j4;
        const float* p = cc + ((size_t)b * NC_ + c) * NB_ + src;
        float4 v;
        if (src + 3 < NB_) v = *(const float4*)p;
        else {
            v.x = (src     < NB_) ? p[0] : 0.f;
            v.y = (src + 1 < NB_) ? p[1] : 0.f;
            v.z = (src + 2 < NB_) ? p[2] : 0.f;
            v.w = (src + 3 < NB_) ? p[3] : 0.f;
        }
        *(float4*)&ccs[c * 512 + j4] = v;
    }
    for (int idx = tid; idx < NC_ * 256; idx += 256) {
        int c = idx >> 8, k = idx & 255;
        cfs[idx] = (k < NF_) ? (double)cf[c * NF_ + k] : 0.0;
    }
    __syncthreads();

    double a0 = 0, a1 = 0, a2 = 0, a3 = 0;
    int base = lane * 4;
    for (int c = wv; c < NC_; c += 4) {
        const float*  row  = &ccs[c * 512];
        const double* crow = &cfs[c * 256];
        float4 cur = *(const float4*)&row[base];
        for (int k4 = 0; k4 < 252; k4 += 4) {
            float4 nxt = *(const float4*)&row[base + k4 + 4];
            double e0 = cur.x, e1 = cur.y, e2 = cur.z, e3 = cur.w;
            double e4 = nxt.x, e5 = nxt.y, e6 = nxt.z;
            double c0 = crow[k4], c1 = crow[k4 + 1], c2 = crow[k4 + 2], c3 = crow[k4 + 3];
            a0 += e0 * c0 + e1 * c1 + e2 * c2 + e3 * c3;
            a1 += e1 * c0 + e2 * c1 + e3 * c2 + e4 * c3;
            a2 += e2 * c0 + e3 * c1 + e4 * c2 + e5 * c3;
            a3 += e3 * c0 + e4 * c1 + e5 * c2 + e6 * c3;
            cur = nxt;
        }
    }
    if (wv > 0) {
        red[wv - 1][lane][0] = a0; red[wv - 1][lane][1] = a1;
        red[wv - 1][lane][2] = a2; red[wv - 1][lane][3] = a3;
    }
    __syncthreads();
    if (wv == 0) {
        a0 += red[0][lane][0] + red[1][lane][0] + red[2][lane][0];
        a1 += red[0][lane][1] + red[1][lane][1] + red[2][lane][1];
        a2 += red[0][lane][2] + red[1][lane][2] + red[2][lane][2];
        a3 += red[0][lane][3] + red[1][lane][3] + red[2][lane][3];
        double gb = (double)bias[0];
        double sd = sdot[b];
        double accs[4] = {a0, a1, a2, a3};
        int tb = t0 + base;
        for (int i = 0; i < 4; ++i) {
            int t = tb + i;
            if (t < LS_) gensig[(size_t)b * LS_ + t] = sd * ft[t] + gb + accs[i];
        }
    }
}

// ---------------- scan: i8-MFMA far + scatter near recursion, wave-specialized ----
// Waves 0..3 (scan): one wave per 16 chains. Waves 4..7 (prep): logit producers.
// NEAR (new): each lane of a chain-quad redundantly holds acc[0..15] (i64@2^45),
//   initialized to -thr[step]. Spike t: acc[t] > 0; scatter tap[k-t] into acc[k>t].
//   Chain per step = cmp -> cndmask -> add64 (no DPP). Taps wave-uniform in SGPRs.
// Prep lane l computes lu for (chain l>>2, step 4*(l&3)+e) into luring[slot][swv][e*64+l].
__global__ __launch_bounds__(512, 2) void k_scan(const double* __restrict__ gensig,
                                                 const float* __restrict__ u,
                                                 const float* __restrict__ iss,
                                                 const float* __restrict__ ff,
                                                 float* __restrict__ out) {
    __shared__ double farT_all[4][16 * 17];          // 8.5 KB (scan waves only)
    __shared__ double luring[2][4][4 * 64];          // 16 KB: [slot][scanwave][e*64+lane]
    int tid = threadIdx.x;
    int wv = tid >> 6, l = tid & 63;
    int swv = wv & 3;
    const bool isPrep = (wv >= 4);
    int gw = blockIdx.x * 4 + swv;
    int b = gw >> 3, rbase = (gw & 7) * 16;
    double* farT = &farT_all[swv][0];

    int lw = l & 15;
    int q  = l >> 4;
    int cn = l >> 2;
    int j  = l & 3;

    const double* gs   = gensig + (size_t)b * LS_;
    const float*  up   = u + b * R_ + rbase + cn;
    float*        op   = out + ((size_t)(b * R_ + rbase + cn)) * NB_ + NF_;
    const float*  issb = iss + b * NF_;

    // scan-wave state
    unsigned long long W0 = 0, W1 = 0, W2 = 0, W3 = 0;
    v4i Bf[4][6];
    long long acc[16];
#pragma unroll
    for (int k = 0; k < 16; ++k) acc[k] = 0;
    long long tqs[15];                 // wave-uniform taps (SGPR via readfirstlane)
#pragma unroll
    for (int k = 0; k < 15; ++k) tqs[k] = 0;
    double gprep = 0.0;
    // prep-wave state
    float ur0 = 0.f, ur1 = 0.f, ur2 = 0.f, ur3 = 0.f;

    if (!isPrep) {
        // ---- iss -> out[.., 0:250] ----
        for (int idx = l; idx < 16 * NF_; idx += 64) {
            int c = idx / NF_, k = idx - c * NF_;
            out[((size_t)(b * R_ + rbase + c)) * NB_ + k] = issb[k];
        }
        // ---- window: bit k = spike(t0-250+k) ----
        for (int k = 0; k < NF_; ++k) {
            unsigned long long bit = (issb[k] > 0.5f) ? 1ull : 0ull;
            if      (k <  64) W0 |= bit << k;
            else if (k < 128) W1 |= bit << (k - 64);
            else if (k < 192) W2 |= bit << (k - 128);
            else              W3 |= bit << (k - 192);
        }
        // ---- B: F[k][n] = ff[k-n]; 6 signed base-256 digit planes @2^48 ----
        int Bword[4][6][4];
#pragma unroll
        for (int kc = 0; kc < 4; ++kc)
#pragma unroll
            for (int p = 0; p < 6; ++p)
#pragma unroll
                for (int w = 0; w < 4; ++w) Bword[kc][p][w] = 0;
#pragma unroll
        for (int kc = 0; kc < 4; ++kc) {
#pragma unroll
            for (int jj = 0; jj < 16; ++jj) {
                int k = kc * 64 + q * 16 + jj;
                int idx = k - lw;
                long long v = 0;
                if (idx >= 0 && idx < NF_)
                    v = __double2ll_rn((double)ff[idx] * 281474976710656.0);   // * 2^48
#pragma unroll
                for (int p = 0; p < 6; ++p) {
                    int d = (int)((v + 128) & 255) - 128;
                    v = (v - (long long)d) >> 8;
                    Bword[kc][p][jj >> 2] |= (d & 255) << ((jj & 3) * 8);
                }
            }
        }
#pragma unroll
        for (int kc = 0; kc < 4; ++kc)
#pragma unroll
            for (int p = 0; p < 6; ++p) {
                v4i t; t.x = Bword[kc][p][0]; t.y = Bword[kc][p][1];
                t.z = Bword[kc][p][2]; t.w = Bword[kc][p][3];
                Bf[kc][p] = t;
            }
        // near taps i64@2^45 (age a = i+1 -> ff[249-i]); uniform -> SGPRs
#pragma unroll
        for (int i = 0; i < 15; ++i) {
            long long v = __double2ll_rn((double)ff[249 - i] * 0x1p45);
            int lo = __builtin_amdgcn_readfirstlane((int)v);
            int hi = __builtin_amdgcn_readfirstlane((int)(v >> 32));
            tqs[i] = ((long long)(unsigned)lo) | ((long long)hi << 32);
        }
    } else {
        // ---- prep prologue: lu(0) -> slot0, lu(1) -> slot1, prefetch u(block 2) ----
        ur0 = up[(size_t)(4 * j + 0) * BR_];
        ur1 = up[(size_t)(4 * j + 1) * BR_];
        ur2 = up[(size_t)(4 * j + 2) * BR_];
        ur3 = up[(size_t)(4 * j + 3) * BR_];
        luring[0][swv][  0 + l] = logit_fast(ur0);
        luring[0][swv][ 64 + l] = logit_fast(ur1);
        luring[0][swv][128 + l] = logit_fast(ur2);
        luring[0][swv][192 + l] = logit_fast(ur3);
        ur0 = up[(size_t)(16 + 4 * j + 0) * BR_];
        ur1 = up[(size_t)(16 + 4 * j + 1) * BR_];
        ur2 = up[(size_t)(16 + 4 * j + 2) * BR_];
        ur3 = up[(size_t)(16 + 4 * j + 3) * BR_];
        luring[1][swv][  0 + l] = logit_fast(ur0);
        luring[1][swv][ 64 + l] = logit_fast(ur1);
        luring[1][swv][128 + l] = logit_fast(ur2);
        luring[1][swv][192 + l] = logit_fast(ur3);
        ur0 = up[(size_t)(32 + 4 * j + 0) * BR_];
        ur1 = up[(size_t)(32 + 4 * j + 1) * BR_];
        ur2 = up[(size_t)(32 + 4 * j + 2) * BR_];
        ur3 = up[(size_t)(32 + 4 * j + 3) * BR_];
    }

    // far phase: fb[chain=q*4+r][step=lw] = gp + sum_k W[k]*ff[k-lw]
    auto do_far = [&](double gp) {
        unsigned long long Sarr[4] = {W0, W1, W2, W3};
        v4i accm[6];
#pragma unroll
        for (int p = 0; p < 6; ++p) accm[p] = (v4i){0, 0, 0, 0};
#pragma unroll
        for (int kc = 0; kc < 4; ++kc) {
            unsigned f = (unsigned)((Sarr[kc] >> (q * 16)) & 0xFFFFull);
            v4i av;
            av.x = (int)((((f      ) & 0xFu) * 0x00204081u) & 0x01010101u);
            av.y = (int)((((f >>  4) & 0xFu) * 0x00204081u) & 0x01010101u);
            av.z = (int)((((f >>  8) & 0xFu) * 0x00204081u) & 0x01010101u);
            av.w = (int)((((f >> 12) & 0xFu) * 0x00204081u) & 0x01010101u);
#pragma unroll
            for (int p = 0; p < 6; ++p)
                accm[p] = __builtin_amdgcn_mfma_i32_16x16x64_i8(av, Bf[kc][p], accm[p], 0, 0, 0);
        }
#pragma unroll
        for (int r = 0; r < 4; ++r) {
            int lo = accm[0][r] + accm[1][r] * 256 + accm[2][r] * 65536;
            int hi = accm[3][r] + accm[4][r] * 256 + accm[5][r] * 65536;
            double fb = gp + (double)lo * 0x1p-48 + (double)hi * 0x1p-24;
            farT[(q * 4 + r) * 17 + lw] = fb;
        }
    };

    // acc init from lu (4 own steps) + farT, then quad-broadcast all 16
#define ACC_INIT(LU0, LU1, LU2, LU3) { \
    long long own0 = -thrq_of(LU0, farT[cn * 17 + 4 * j + 0]); \
    long long own1 = -thrq_of(LU1, farT[cn * 17 + 4 * j + 1]); \
    long long own2 = -thrq_of(LU2, farT[cn * 17 + 4 * j + 2]); \
    long long own3 = -thrq_of(LU3, farT[cn * 17 + 4 * j + 3]); \
    acc[ 0] = dpp64i<0x00>(own0); acc[ 1] = dpp64i<0x00>(own1); \
    acc[ 2] = dpp64i<0x00>(own2); acc[ 3] = dpp64i<0x00>(own3); \
    acc[ 4] = dpp64i<0x55>(own0); acc[ 5] = dpp64i<0x55>(own1); \
    acc[ 6] = dpp64i<0x55>(own2); acc[ 7] = dpp64i<0x55>(own3); \
    acc[ 8] = dpp64i<0xAA>(own0); acc[ 9] = dpp64i<0xAA>(own1); \
    acc[10] = dpp64i<0xAA>(own2); acc[11] = dpp64i<0xAA>(own3); \
    acc[12] = dpp64i<0xFF>(own0); acc[13] = dpp64i<0xFF>(own1); \
    acc[14] = dpp64i<0xFF>(own2); acc[15] = dpp64i<0xFF>(own3); \
}

    __syncthreads();   // A: prep's lu(0), lu(1) visible to scan waves

    if (!isPrep) {
        // ---- scan prologue: block 0 ----
        gprep = gs[lw];
        do_far(gprep);
        double lu0 = luring[0][swv][  0 + l];
        double lu1 = luring[0][swv][ 64 + l];
        double lu2 = luring[0][swv][128 + l];
        double lu3 = luring[0][swv][192 + l];
        __asm__ volatile("s_waitcnt lgkmcnt(0)" ::: "memory");
        ACC_INIT(lu0, lu1, lu2, lu3)
        { int tg = 16 + lw; if (tg > LS_ - 1) tg = LS_ - 1; gprep = gs[tg]; }
    }

    __syncthreads();   // B: scan's slot0 (lu(0)) reads done before prep overwrites it

    int blk = 0;
    for (int t0 = 0; t0 < LS_; t0 += H_, ++blk) {
        if (!isPrep) {
            // ---- NEAR: 16 steps, scatter form. Chain: cmp -> cndmask -> add64 ----
            unsigned qreg = 0;
#pragma unroll
            for (int t = 0; t < 16; ++t) {
                bool sp = acc[t] > 0;
                qreg |= (sp ? (1u << t) : 0u);
#pragma unroll
                for (int k = t + 1; k < 16; ++k)
                    acc[k] += sp ? tqs[k - t - 1] : 0LL;
            }
            unsigned q2 = qreg;                       // bit i = spike(t0+i)

            // ---- store spikes ----
            int rem = LS_ - t0; if (rem > H_) rem = H_;
            int s0 = 4 * j;
            if (s0 + 3 < rem) {
                float4 o;
                o.x = (float)((q2 >> (s0    )) & 1u);
                o.y = (float)((q2 >> (s0 + 1)) & 1u);
                o.z = (float)((q2 >> (s0 + 2)) & 1u);
                o.w = (float)((q2 >> (s0 + 3)) & 1u);
                *(float4*)(op + t0 + s0) = o;
            } else {
#pragma unroll
                for (int e = 0; e < 4; ++e)
                    if (s0 + e < rem) op[t0 + s0 + e] = (float)((q2 >> (s0 + e)) & 1u);
            }

            if (t0 + H_ < LS_) {
                // lu(blk+1) was written by prep last iteration; issue reads early
                double lu0 = luring[(blk + 1) & 1][swv][  0 + l];
                double lu1 = luring[(blk + 1) & 1][swv][ 64 + l];
                double lu2 = luring[(blk + 1) & 1][swv][128 + l];
                double lu3 = luring[(blk + 1) & 1][swv][192 + l];

                // advance per-chain window with chain lw's new spikes
                int q2i = __builtin_amdgcn_ds_bpermute(lw << 4, (int)q2);
                unsigned long long q2n = (unsigned long long)(unsigned)q2i;
                W0 = (W0 >> 16) | (W1 << 48);
                W1 = (W1 >> 16) | (W2 << 48);
                W2 = (W2 >> 16) | (W3 << 48);
                W3 = (W3 >> 16) | (q2n << 42);

                do_far(gprep);                                  // block t0+16
                __asm__ volatile("s_waitcnt lgkmcnt(0)" ::: "memory");
                ACC_INIT(lu0, lu1, lu2, lu3)

                int tg = t0 + 32 + lw; if (tg > LS_ - 1) tg = LS_ - 1;
                gprep = gs[tg];
            }
        } else {
            // ---- prep: lu(blk+2) -> slot[blk&1]; prefetch u(block blk+3) ----
            if (blk <= NBLK_ - 3) {
                double lu0 = logit_fast(ur0), lu1 = logit_fast(ur1);
                double lu2 = logit_fast(ur2), lu3 = logit_fast(ur3);
                luring[blk & 1][swv][  0 + l] = lu0;
                luring[blk & 1][swv][ 64 + l] = lu1;
                luring[blk & 1][swv][128 + l] = lu2;
                luring[blk & 1][swv][192 + l] = lu3;
                if (blk <= NBLK_ - 4) {
                    int T = (blk + 3) * H_;
                    int t_;
                    t_ = T + 4 * j + 0; if (t_ > LS_ - 1) t_ = LS_ - 1; ur0 = up[(size_t)t_ * BR_];
                    t_ = T + 4 * j + 1; if (t_ > LS_ - 1) t_ = LS_ - 1; ur1 = up[(size_t)t_ * BR_];
                    t_ = T + 4 * j + 2; if (t_ > LS_ - 1) t_ = LS_ - 1; ur2 = up[(size_t)t_ * BR_];
                    t_ = T + 4 * j + 3; if (t_ > LS_ - 1) t_ = LS_ - 1; ur3 = up[(size_t)t_ * BR_];
                }
            }
        }
        __syncthreads();   // paces ring: write(t) | bar | read(t+1) | bar | overwrite(t+2)
    }
#undef ACC_INIT

    (void)lw;
}

extern "C" void kernel_launch(void* const* d_in, const int* in_sizes, int n_in,
                              void* d_out, int out_size, void* d_ws, size_t ws_size,
                              hipStream_t stream) {
    const float* stim_spat = (const float*)d_in[0];   // (128,2048)
    const float* stim_time = (const float*)d_in[1];   // (2000,)
    const float* iss       = (const float*)d_in[2];   // (128,250)
    const float* cc        = (const float*)d_in[3];   // (128,16,2000)
    const float* sf        = (const float*)d_in[4];   // (2048,)
    const float* bias      = (const float*)d_in[5];   // (1,)
    const float* stf       = (const float*)d_in[6];   // (250,)
    const float* ff        = (const float*)d_in[7];   // (250,)
    const float* cf        = (const float*)d_in[8];   // (16,250)
    const float* u         = (const float*)d_in[9];   // (1750,128,128)
    (void)in_sizes; (void)n_in; (void)out_size; (void)ws_size;

    float* out = (float*)d_out;                       // (128,128,2000)

    double* ws     = (double*)d_ws;
    double* gensig = ws;                              // 128*1750 f64
    double* ft     = gensig + (size_t)B_ * LS_;       // 1751 f64
    double* sdot   = ft + NT_;                        // 128 f64

    k_pre  <<<135, 256, 0, stream>>>(stim_time, stf, stim_spat, sf, ft, sdot);
    k_coup <<<dim3(7, B_), 256, 0, stream>>>(cc, cf, sdot, ft, bias, gensig);
    k_scan <<<B_ * 2, 512, 0, stream>>>(gensig, u, iss, ff, out);
}

// Round 3
// 562.742 us; speedup vs baseline: 1.2786x; 1.2786x over previous
//
#include <hip/hip_runtime.h>
#include <math.h>

#define B_  128
#define P_  2048
#define NB_ 2000
#define NF_ 250
#define NC_ 16
#define R_  128
#define LS_ 1750   // NB-NF (len_sim)
#define NT_ 1751   // NB-NF+1
#define BR_ (B_ * R_)
#define H_  16     // steps per block
#define NBLK_ 110  // number of 16-step blocks covering LS_ (t0 = 0..1744)

typedef int v4i __attribute__((ext_vector_type(4)));

// ---- per-lane select: bit[lane] of m ? b : a (mask in SGPR pair) ----
__device__ __forceinline__ unsigned csel32(unsigned a, unsigned b, unsigned long long m) {
    unsigned r;
    asm("v_cndmask_b32 %0, %1, %2, %3" : "=v"(r) : "v"(a), "v"(b), "s"(m));
    return r;
}

// ---- per-lane f64 select: bit[lane] of m ? t : 0.0 ----
__device__ __forceinline__ double dsel2(double t, unsigned long long m) {
    long long tb = __double_as_longlong(t);
    int tlo = (int)tb, thi = (int)(tb >> 32);
    int rlo, rhi;
    asm("v_cndmask_b32 %0, 0, %2, %4\n\t"
        "v_cndmask_b32 %1, 0, %3, %4"
        : "=&v"(rlo), "=&v"(rhi)
        : "v"(tlo), "v"(thi), "s"(m));
    return __longlong_as_double(((long long)(unsigned)rlo) | ((long long)rhi << 32));
}

// ---- f64 AND with 0/-1 int mask ----
__device__ __forceinline__ double dand(double t, int m) {
    return __longlong_as_double(__double_as_longlong(t) & (long long)m);
}

// ---- fast f64 divide: rcp + 2 NR + residual correction (err ~1e-16) ----
__device__ __forceinline__ double fdiv_fast(double a, double b) {
    double r;
    asm("v_rcp_f64 %0, %1" : "=v"(r) : "v"(b));
    r = fma(fma(-b, r, 1.0), r, r);
    r = fma(fma(-b, r, 1.0), r, r);
    double q = a * r;
    q = fma(fma(-b, q, a), r, q);
    return q;
}

// ---- custom logit: log(u/(1-u)) f64, abs err < 1e-9 (margin ~2e-7) ----
__device__ __forceinline__ double logit_fast(float uf) {
    double u = (double)uf;
    double v = 1.0 - u;                  // exact (u has 24-bit mantissa)
    double qd = fdiv_fast(u, v);
    long long bits = __double_as_longlong(qd);
    int e = (int)((bits >> 52) & 0x7FF) - 1023;
    double m = __longlong_as_double((bits & 0xFFFFFFFFFFFFFLL) | 0x3FF0000000000000LL);
    if (m > 1.4142135623730951) { m *= 0.5; e += 1; }   // m in [0.707,1.414]
    double s = fdiv_fast(m - 1.0, m + 1.0);             // |s| <= 0.1716
    double z = s * s;
    double Q = fma(z, fma(z, fma(z, fma(z,
        0.09090909090909091, 0.1111111111111111),
        0.14285714285714285), 0.2), 0.3333333333333333);
    double logm = fma(2.0 * s, z * Q, 2.0 * s);         // 2*atanh(s)
    return fma((double)e, 0.6931471805599453, logm);
}

// ---------------- fused: ft (blocks 0..6) + sdot (blocks 7..134) ----------------
__global__ __launch_bounds__(256) void k_pre(const float* __restrict__ st,
                                             const float* __restrict__ stf,
                                             const float* __restrict__ sp,
                                             const float* __restrict__ sf,
                                             double* __restrict__ ft,
                                             double* __restrict__ sdot) {
    if (blockIdx.x < 7) {
        int t = blockIdx.x * 256 + threadIdx.x;
        if (t >= NT_) return;
        double s = 0.0;
        for (int k = 0; k < NF_; ++k) s += (double)st[t + k] * (double)stf[k];
        ft[t] = s;
    } else {
        __shared__ double red[256];
        int b = blockIdx.x - 7;
        double s = 0.0;
        for (int p = threadIdx.x; p < P_; p += 256)
            s += (double)sp[(size_t)b * P_ + p] * (double)sf[p];
        red[threadIdx.x] = s;
        __syncthreads();
        for (int off = 128; off > 0; off >>= 1) {
            if (threadIdx.x < off) red[threadIdx.x] += red[threadIdx.x + off];
            __syncthreads();
        }
        if (threadIdx.x == 0) sdot[b] = red[0];
    }
}

// ---------------- gensig[b,t] = sdot[b]*ft[t] + bias + coup[b,t], f64 ----------------
__global__ __launch_bounds__(256) void k_coup(const float* __restrict__ cc,
                                              const float* __restrict__ cf,
                                              const double* __restrict__ sdot,
                                              const double* __restrict__ ft,
                                              const float* __restrict__ bias,
                                              double* __restrict__ gensig) {
    __shared__ __align__(16) float  ccs[NC_ * 512];   // 32 KB
    __shared__ __align__(16) double cfs[NC_ * 256];   // 32 KB
    __shared__ double red[3][64][4];                  // 6 KB
    int b = blockIdx.y, t0 = blockIdx.x * 256;
    int tid = threadIdx.x, lane = tid & 63, wv = tid >> 6;

    for (int idx = tid; idx < NC_ * 128; idx += 256) {
        int c = idx >> 7, j4 = (idx & 127) * 4, src = t0 + j4;
        const float* p = cc + ((size_t)b * NC_ + c) * NB_ + src;
        float4 v;
        if (src + 3 < NB_) v = *(const float4*)p;
        else {
            v.x = (src     < NB_) ? p[0] : 0.f;
            v.y = (src + 1 < NB_) ? p[1] : 0.f;
            v.z = (src + 2 < NB_) ? p[2] : 0.f;
            v.w = (src + 3 < NB_) ? p[3] : 0.f;
        }
        *(float4*)&ccs[c * 512 + j4] = v;
    }
    for (int idx = tid; idx < NC_ * 256; idx += 256) {
        int c = idx >> 8, k = idx & 255;
        cfs[idx] = (k < NF_) ? (double)cf[c * NF_ + k] : 0.0;
    }
    __syncthreads();

    double a0 = 0, a1 = 0, a2 = 0, a3 = 0;
    int base = lane * 4;
    for (int c = wv; c < NC_; c += 4) {
        const float*  row  = &ccs[c * 512];
        const double* crow = &cfs[c * 256];
        float4 cur = *(const float4*)&row[base];
        for (int k4 = 0; k4 < 252; k4 += 4) {
            float4 nxt = *(const float4*)&row[base + k4 + 4];
            double e0 = cur.x, e1 = cur.y, e2 = cur.z, e3 = cur.w;
            double e4 = nxt.x, e5 = nxt.y, e6 = nxt.z;
            double c0 = crow[k4], c1 = crow[k4 + 1], c2 = crow[k4 + 2], c3 = crow[k4 + 3];
            a0 += e0 * c0 + e1 * c1 + e2 * c2 + e3 * c3;
            a1 += e1 * c0 + e2 * c1 + e3 * c2 + e4 * c3;
            a2 += e2 * c0 + e3 * c1 + e4 * c2 + e5 * c3;
            a3 += e3 * c0 + e4 * c1 + e5 * c2 + e6 * c3;
            cur = nxt;
        }
    }
    if (wv > 0) {
        red[wv - 1][lane][0] = a0; red[wv - 1][lane][1] = a1;
        red[wv - 1][lane][2] = a2; red[wv - 1][lane][3] = a3;
    }
    __syncthreads();
    if (wv == 0) {
        a0 += red[0][lane][0] + red[1][lane][0] + red[2][lane][0];
        a1 += red[0][lane][1] + red[1][lane][1] + red[2][lane][1];
        a2 += red[0][lane][2] + red[1][lane][2] + red[2][lane][2];
        a3 += red[0][lane][3] + red[1][lane][3] + red[2][lane][3];
        double gb = (double)bias[0];
        double sd = sdot[b];
        double accs[4] = {a0, a1, a2, a3};
        int tb = t0 + base;
        for (int i = 0; i < 4; ++i) {
            int t = tb + i;
            if (t < LS_) gensig[(size_t)b * LS_ + t] = sd * ft[t] + gb + accs[i];
        }
    }
}

// ---------------- scan: i8-MFMA far + ballot/SALU near recursion ----
// Waves 0..3 (scan): one wave per 16 chains. Waves 4..7 (prep): logit producers.
// NEAR: per step t, spike(t) depends on older spikes only through age-1. Both
//   outcomes are balloted (b0: no age-1 spike, b1: with), and the serial
//   recurrence is a pure SALU bitwise mux over wave masks:
//     SP_t = b0n ^ (SP_{t-1} & (b1n^b0n)), normalized+quad-spread.
//   Ages 2..6 enter per-step via cndmask-with-SGPR-mask f64 selects (>=2-step
//   slack); ages 7..15 via a per-round spike-register snapshot + sbfe sign
//   masks (>=3-step slack). All f64 (no i64 quant; errors ~1e-15 << margin).
// Lane j of a chain-quad owns steps {4e+j}; its slot-e regs (thr, XB) are for
//   step 4e+j; ballots collect all 4 lanes' step-bits per round position.
__global__ __launch_bounds__(512, 2) void k_scan(const double* __restrict__ gensig,
                                                 const float* __restrict__ u,
                                                 const float* __restrict__ iss,
                                                 const float* __restrict__ ff,
                                                 float* __restrict__ out) {
    __shared__ double farT_all[4][16 * 17];          // 8.5 KB (scan waves only)
    __shared__ double luring[2][4][4 * 64];          // 16 KB: [slot][scanwave][e*64+lane]
    int tid = threadIdx.x;
    int wv = tid >> 6, l = tid & 63;
    int swv = wv & 3;
    const bool isPrep = (wv >= 4);
    int gw = blockIdx.x * 4 + swv;
    int b = gw >> 3, rbase = (gw & 7) * 16;
    double* farT = &farT_all[swv][0];

    int lw = l & 15;
    int q  = l >> 4;
    int cn = l >> 2;
    int j  = l & 3;
    int jo = 16 + j;            // sbfe offset base: bit(16 + t - a) with t = 4e+j

    const double* gs   = gensig + (size_t)b * LS_;
    const float*  up   = u + b * R_ + rbase + cn;
    float*        op   = out + ((size_t)(b * R_ + rbase + cn)) * NB_ + NF_;
    const float*  issb = iss + b * NF_;

    // scan-wave state
    unsigned long long W0 = 0, W1 = 0, W2 = 0, W3 = 0;
    v4i Bf[4][6];
    double T1d = 0, T2d = 0, T3d = 0, T4d = 0, T5d = 0, T6d = 0;
    double tp7 = 0, tp8 = 0, tp9 = 0, tp10 = 0, tp11 = 0, tp12 = 0, tp13 = 0, tp14 = 0;
    double tp15 = 0;
    double thr0 = 0, thr1 = 0, thr2 = 0, thr3 = 0;
    double gprep = 0.0;
    // prep-wave state
    float ur0 = 0.f, ur1 = 0.f, ur2 = 0.f, ur3 = 0.f;

    if (!isPrep) {
        // ---- iss -> out[.., 0:250] ----
        for (int idx = l; idx < 16 * NF_; idx += 64) {
            int c = idx / NF_, k = idx - c * NF_;
            out[((size_t)(b * R_ + rbase + c)) * NB_ + k] = issb[k];
        }
        // ---- window: bit k = spike(t0-250+k) ----
        for (int k = 0; k < NF_; ++k) {
            unsigned long long bit = (issb[k] > 0.5f) ? 1ull : 0ull;
            if      (k <  64) W0 |= bit << k;
            else if (k < 128) W1 |= bit << (k - 64);
            else if (k < 192) W2 |= bit << (k - 128);
            else              W3 |= bit << (k - 192);
        }
        // ---- B: F[k][n] = ff[k-n]; 6 signed base-256 digit planes @2^48 ----
        int Bword[4][6][4];
#pragma unroll
        for (int kc = 0; kc < 4; ++kc)
#pragma unroll
            for (int p = 0; p < 6; ++p)
#pragma unroll
                for (int w = 0; w < 4; ++w) Bword[kc][p][w] = 0;
#pragma unroll
        for (int kc = 0; kc < 4; ++kc) {
#pragma unroll
            for (int jj = 0; jj < 16; ++jj) {
                int k = kc * 64 + q * 16 + jj;
                int idx = k - lw;
                long long v = 0;
                if (idx >= 0 && idx < NF_)
                    v = __double2ll_rn((double)ff[idx] * 281474976710656.0);   // * 2^48
#pragma unroll
                for (int p = 0; p < 6; ++p) {
                    int d = (int)((v + 128) & 255) - 128;
                    v = (v - (long long)d) >> 8;
                    Bword[kc][p][jj >> 2] |= (d & 255) << ((jj & 3) * 8);
                }
            }
        }
#pragma unroll
        for (int kc = 0; kc < 4; ++kc)
#pragma unroll
            for (int p = 0; p < 6; ++p) {
                v4i t; t.x = Bword[kc][p][0]; t.y = Bword[kc][p][1];
                t.z = Bword[kc][p][2]; t.w = Bword[kc][p][3];
                Bf[kc][p] = t;
            }
        // near taps, f64: age a -> ff[250-a]
        T1d  = (double)ff[249]; T2d  = (double)ff[248]; T3d  = (double)ff[247];
        T4d  = (double)ff[246]; T5d  = (double)ff[245]; T6d  = (double)ff[244];
        tp7  = (double)ff[243]; tp8  = (double)ff[242]; tp9  = (double)ff[241];
        tp10 = (double)ff[240]; tp11 = (double)ff[239]; tp12 = (double)ff[238];
        tp13 = (double)ff[237]; tp14 = (double)ff[236]; tp15 = (double)ff[235];
    } else {
        // ---- prep prologue: lu(0) -> slot0, lu(1) -> slot1, prefetch u(block 2) ----
        ur0 = up[(size_t)(0  + j) * BR_];
        ur1 = up[(size_t)(4  + j) * BR_];
        ur2 = up[(size_t)(8  + j) * BR_];
        ur3 = up[(size_t)(12 + j) * BR_];
        luring[0][swv][  0 + l] = logit_fast(ur0);
        luring[0][swv][ 64 + l] = logit_fast(ur1);
        luring[0][swv][128 + l] = logit_fast(ur2);
        luring[0][swv][192 + l] = logit_fast(ur3);
        ur0 = up[(size_t)(16 + j) * BR_];
        ur1 = up[(size_t)(20 + j) * BR_];
        ur2 = up[(size_t)(24 + j) * BR_];
        ur3 = up[(size_t)(28 + j) * BR_];
        luring[1][swv][  0 + l] = logit_fast(ur0);
        luring[1][swv][ 64 + l] = logit_fast(ur1);
        luring[1][swv][128 + l] = logit_fast(ur2);
        luring[1][swv][192 + l] = logit_fast(ur3);
        ur0 = up[(size_t)(32 + j) * BR_];
        ur1 = up[(size_t)(36 + j) * BR_];
        ur2 = up[(size_t)(40 + j) * BR_];
        ur3 = up[(size_t)(44 + j) * BR_];
    }

    // far phase: fb[chain=q*4+r][step=lw] = gp + sum_k W[k]*ff[k-lw]
    auto do_far = [&](double gp) {
        unsigned long long Sarr[4] = {W0, W1, W2, W3};
        v4i accm[6];
#pragma unroll
        for (int p = 0; p < 6; ++p) accm[p] = (v4i){0, 0, 0, 0};
#pragma unroll
        for (int kc = 0; kc < 4; ++kc) {
            unsigned f = (unsigned)((Sarr[kc] >> (q * 16)) & 0xFFFFull);
            v4i av;
            av.x = (int)((((f      ) & 0xFu) * 0x00204081u) & 0x01010101u);
            av.y = (int)((((f >>  4) & 0xFu) * 0x00204081u) & 0x01010101u);
            av.z = (int)((((f >>  8) & 0xFu) * 0x00204081u) & 0x01010101u);
            av.w = (int)((((f >> 12) & 0xFu) * 0x00204081u) & 0x01010101u);
#pragma unroll
            for (int p = 0; p < 6; ++p)
                accm[p] = __builtin_amdgcn_mfma_i32_16x16x64_i8(av, Bf[kc][p], accm[p], 0, 0, 0);
        }
#pragma unroll
        for (int r = 0; r < 4; ++r) {
            int lo = accm[0][r] + accm[1][r] * 256 + accm[2][r] * 65536;
            int hi = accm[3][r] + accm[4][r] * 256 + accm[5][r] * 65536;
            double fb = gp + (double)lo * 0x1p-48 + (double)hi * 0x1p-24;
            farT[(q * 4 + r) * 17 + lw] = fb;
        }
    };

    // ages 7..15 partial sum for round E (qsnap holds spike bits <= 4E-4 at 16+t)
    auto xbcalc = [&](int e4, unsigned qsnap) -> double {
        unsigned qs = qsnap >> e4;
        double x = (dand(tp7,  __builtin_amdgcn_sbfe((int)qs, jo - 7,  1)) +
                    dand(tp8,  __builtin_amdgcn_sbfe((int)qs, jo - 8,  1))) +
                   (dand(tp9,  __builtin_amdgcn_sbfe((int)qs, jo - 9,  1)) +
                    dand(tp10, __builtin_amdgcn_sbfe((int)qs, jo - 10, 1)));
        double y = (dand(tp11, __builtin_amdgcn_sbfe((int)qs, jo - 11, 1)) +
                    dand(tp12, __builtin_amdgcn_sbfe((int)qs, jo - 12, 1))) +
                   (dand(tp13, __builtin_amdgcn_sbfe((int)qs, jo - 13, 1)) +
                    dand(tp14, __builtin_amdgcn_sbfe((int)qs, jo - 14, 1)));
        return (x + y) + dand(tp15, __builtin_amdgcn_sbfe((int)qs, jo - 15, 1));
    };

    __syncthreads();   // A: prep's lu(0), lu(1) visible to scan waves

    if (!isPrep) {
        // ---- scan prologue: block 0 ----
        gprep = gs[lw];
        do_far(gprep);
        double lu0 = luring[0][swv][  0 + l];
        double lu1 = luring[0][swv][ 64 + l];
        double lu2 = luring[0][swv][128 + l];
        double lu3 = luring[0][swv][192 + l];
        __asm__ volatile("s_waitcnt lgkmcnt(0)" ::: "memory");
        thr0 = lu0 - farT[cn * 17 +  0 + j];
        thr1 = lu1 - farT[cn * 17 +  4 + j];
        thr2 = lu2 - farT[cn * 17 +  8 + j];
        thr3 = lu3 - farT[cn * 17 + 12 + j];
        { int tg = 16 + lw; if (tg > LS_ - 1) tg = LS_ - 1; gprep = gs[tg]; }
    }

    __syncthreads();   // B: scan's slot0 (lu(0)) reads done before prep overwrites it

// one near step: T literal, XB/THR the round's regs
#define STEP(T, XB, THR) { \
    double s23 = dsel2(T2d, sp2) + dsel2(T3d, sp3); \
    double s456 = dsel2(T4d, sp4) + (dsel2(T5d, sp5) + dsel2(T6d, sp6)); \
    double X = (XB) + (s23 + s456); \
    double Y = X + T1d; \
    unsigned long long Bm0 = __ballot(X > (THR)); \
    unsigned long long Bm1 = __ballot(Y > (THR)); \
    unsigned long long b0n = (Bm0 >> ((T) & 3)) & QP; \
    unsigned long long b1n = (Bm1 >> ((T) & 3)) & QP; \
    unsigned long long sn = b0n ^ (sp1 & (b1n ^ b0n)); \
    unsigned long long fl = sn | (sn << 1); fl |= (fl << 2); \
    sp6 = sp5; sp5 = sp4; sp4 = sp3; sp3 = sp2; sp2 = sp1; sp1 = fl; \
    QL = csel32(QL, QL | (1u << (16 + (T))), fl); \
}

    int blk = 0;
    for (int t0 = 0; t0 < LS_; t0 += H_, ++blk) {
        if (!isPrep) {
            // ---- NEAR: ballot + SALU-mux recurrence ----
            const unsigned long long QP = 0x1111111111111111ull;
            unsigned QL = 0;
            unsigned long long sp1 = 0, sp2 = 0, sp3 = 0, sp4 = 0, sp5 = 0, sp6 = 0;
            double XB0 = 0.0, XB1, XB2, XB3;
            STEP(0, XB0, thr0)
            { unsigned qs1 = QL; XB1 = xbcalc(4, qs1); }
            STEP(1, XB0, thr0)
            STEP(2, XB0, thr0)
            STEP(3, XB0, thr0)
            STEP(4, XB1, thr1)
            { unsigned qs2 = QL; XB2 = xbcalc(8, qs2); }
            STEP(5, XB1, thr1)
            STEP(6, XB1, thr1)
            STEP(7, XB1, thr1)
            STEP(8, XB2, thr2)
            { unsigned qs3 = QL; XB3 = xbcalc(12, qs3); }
            STEP(9,  XB2, thr2)
            STEP(10, XB2, thr2)
            STEP(11, XB2, thr2)
            STEP(12, XB3, thr3)
            STEP(13, XB3, thr3)
            STEP(14, XB3, thr3)
            STEP(15, XB3, thr3)
            unsigned q2 = QL >> 16;                    // bit i = spike(t0+i)

            // ---- store spikes ----
            int rem = LS_ - t0; if (rem > H_) rem = H_;
            int s0 = 4 * j;
            if (s0 + 3 < rem) {
                float4 o;
                o.x = (float)((q2 >> (s0    )) & 1u);
                o.y = (float)((q2 >> (s0 + 1)) & 1u);
                o.z = (float)((q2 >> (s0 + 2)) & 1u);
                o.w = (float)((q2 >> (s0 + 3)) & 1u);
                *(float4*)(op + t0 + s0) = o;
            } else {
#pragma unroll
                for (int e = 0; e < 4; ++e)
                    if (s0 + e < rem) op[t0 + s0 + e] = (float)((q2 >> (s0 + e)) & 1u);
            }

            if (t0 + H_ < LS_) {
                // lu(blk+1) was written by prep last iteration; issue reads early
                double lu0 = luring[(blk + 1) & 1][swv][  0 + l];
                double lu1 = luring[(blk + 1) & 1][swv][ 64 + l];
                double lu2 = luring[(blk + 1) & 1][swv][128 + l];
                double lu3 = luring[(blk + 1) & 1][swv][192 + l];

                // advance per-chain window with chain lw's new spikes
                int q2i = __builtin_amdgcn_ds_bpermute(lw << 4, (int)q2);
                unsigned long long q2n = (unsigned long long)(unsigned)q2i;
                W0 = (W0 >> 16) | (W1 << 48);
                W1 = (W1 >> 16) | (W2 << 48);
                W2 = (W2 >> 16) | (W3 << 48);
                W3 = (W3 >> 16) | (q2n << 42);

                do_far(gprep);                                  // block t0+16
                __asm__ volatile("s_waitcnt lgkmcnt(0)" ::: "memory");
                thr0 = lu0 - farT[cn * 17 +  0 + j];
                thr1 = lu1 - farT[cn * 17 +  4 + j];
                thr2 = lu2 - farT[cn * 17 +  8 + j];
                thr3 = lu3 - farT[cn * 17 + 12 + j];

                int tg = t0 + 32 + lw; if (tg > LS_ - 1) tg = LS_ - 1;
                gprep = gs[tg];
            }
        } else {
            // ---- prep: lu(blk+2) -> slot[blk&1]; prefetch u(block blk+3) ----
            if (blk <= NBLK_ - 3) {
                double lu0 = logit_fast(ur0), lu1 = logit_fast(ur1);
                double lu2 = logit_fast(ur2), lu3 = logit_fast(ur3);
                luring[blk & 1][swv][  0 + l] = lu0;
                luring[blk & 1][swv][ 64 + l] = lu1;
                luring[blk & 1][swv][128 + l] = lu2;
                luring[blk & 1][swv][192 + l] = lu3;
                if (blk <= NBLK_ - 4) {
                    int T = (blk + 3) * H_;
                    int t_;
                    t_ = T +  0 + j; if (t_ > LS_ - 1) t_ = LS_ - 1; ur0 = up[(size_t)t_ * BR_];
                    t_ = T +  4 + j; if (t_ > LS_ - 1) t_ = LS_ - 1; ur1 = up[(size_t)t_ * BR_];
                    t_ = T +  8 + j; if (t_ > LS_ - 1) t_ = LS_ - 1; ur2 = up[(size_t)t_ * BR_];
                    t_ = T + 12 + j; if (t_ > LS_ - 1) t_ = LS_ - 1; ur3 = up[(size_t)t_ * BR_];
                }
            }
        }
        __syncthreads();   // paces ring: write(t) | bar | read(t+1) | bar | overwrite(t+2)
    }
#undef STEP
}

extern "C" void kernel_launch(void* const* d_in, const int* in_sizes, int n_in,
                              void* d_out, int out_size, void* d_ws, size_t ws_size,
                              hipStream_t stream) {
    const float* stim_spat = (const float*)d_in[0];   // (128,2048)
    const float* stim_time = (const float*)d_in[1];   // (2000,)
    const float* iss       = (const float*)d_in[2];   // (128,250)
    const float* cc        = (const float*)d_in[3];   // (128,16,2000)
    const float* sf        = (const float*)d_in[4];   // (2048,)
    const float* bias      = (const float*)d_in[5];   // (1,)
    const float* stf       = (const float*)d_in[6];   // (250,)
    const float* ff        = (const float*)d_in[7];   // (250,)
    const float* cf        = (const float*)d_in[8];   // (16,250)
    const float* u         = (const float*)d_in[9];   // (1750,128,128)
    (void)in_sizes; (void)n_in; (void)out_size; (void)ws_size;

    float* out = (float*)d_out;                       // (128,128,2000)

    double* ws     = (double*)d_ws;
    double* gensig = ws;                              // 128*1750 f64
    double* ft     = gensig + (size_t)B_ * LS_;       // 1751 f64
    double* sdot   = ft + NT_;                        // 128 f64

    k_pre  <<<135, 256, 0, stream>>>(stim_time, stf, stim_spat, sf, ft, sdot);
    k_coup <<<dim3(7, B_), 256, 0, stream>>>(cc, cf, sdot, ft, bias, gensig);
    k_scan <<<B_ * 2, 512, 0, stream>>>(gensig, u, iss, ff, out);
}

// Round 4
// 524.577 us; speedup vs baseline: 1.3716x; 1.0728x over previous
//
#include <hip/hip_runtime.h>
#include <math.h>

#define B_  128
#define P_  2048
#define NB_ 2000
#define NF_ 250
#define NC_ 16
#define R_  128
#define LS_ 1750   // NB-NF (len_sim)
#define NT_ 1751   // NB-NF+1
#define BR_ (B_ * R_)
#define H_  16     // steps per block
#define NBLK_ 110  // number of 16-step blocks covering LS_ (t0 = 0..1744)

typedef int v4i __attribute__((ext_vector_type(4)));

// ---- per-lane select: bit[lane] of m ? b : a (mask in SGPR pair) ----
__device__ __forceinline__ unsigned csel32(unsigned a, unsigned b, unsigned long long m) {
    unsigned r;
    asm("v_cndmask_b32 %0, %1, %2, %3" : "=v"(r) : "v"(a), "v"(b), "s"(m));
    return r;
}

// ---- per-lane f64 select: bit[lane] of m ? t : 0.0 ----
__device__ __forceinline__ double dsel2(double t, unsigned long long m) {
    long long tb = __double_as_longlong(t);
    int tlo = (int)tb, thi = (int)(tb >> 32);
    int rlo, rhi;
    asm("v_cndmask_b32 %0, 0, %2, %4\n\t"
        "v_cndmask_b32 %1, 0, %3, %4"
        : "=&v"(rlo), "=&v"(rhi)
        : "v"(tlo), "v"(thi), "s"(m));
    return __longlong_as_double(((long long)(unsigned)rlo) | ((long long)rhi << 32));
}

// ---- f64 AND with 0/-1 int mask ----
__device__ __forceinline__ double dand(double t, int m) {
    return __longlong_as_double(__double_as_longlong(t) & (long long)m);
}

// ---- fast f64 divide: rcp + 2 NR + residual correction (err ~1e-16) ----
__device__ __forceinline__ double fdiv_fast(double a, double b) {
    double r;
    asm("v_rcp_f64 %0, %1" : "=v"(r) : "v"(b));
    r = fma(fma(-b, r, 1.0), r, r);
    r = fma(fma(-b, r, 1.0), r, r);
    double q = a * r;
    q = fma(fma(-b, q, a), r, q);
    return q;
}

// ---- custom logit: log(u/(1-u)) f64, abs err < 1e-9 (margin ~2e-7) ----
__device__ __forceinline__ double logit_fast(float uf) {
    double u = (double)uf;
    double v = 1.0 - u;                  // exact (u has 24-bit mantissa)
    double qd = fdiv_fast(u, v);
    long long bits = __double_as_longlong(qd);
    int e = (int)((bits >> 52) & 0x7FF) - 1023;
    double m = __longlong_as_double((bits & 0xFFFFFFFFFFFFFLL) | 0x3FF0000000000000LL);
    if (m > 1.4142135623730951) { m *= 0.5; e += 1; }   // m in [0.707,1.414]
    double s = fdiv_fast(m - 1.0, m + 1.0);             // |s| <= 0.1716
    double z = s * s;
    double Q = fma(z, fma(z, fma(z, fma(z,
        0.09090909090909091, 0.1111111111111111),
        0.14285714285714285), 0.2), 0.3333333333333333);
    double logm = fma(2.0 * s, z * Q, 2.0 * s);         // 2*atanh(s)
    return fma((double)e, 0.6931471805599453, logm);
}

// ---------------- fused: ft (blocks 0..6) + sdot (blocks 7..134) ----------------
__global__ __launch_bounds__(256) void k_pre(const float* __restrict__ st,
                                             const float* __restrict__ stf,
                                             const float* __restrict__ sp,
                                             const float* __restrict__ sf,
                                             double* __restrict__ ft,
                                             double* __restrict__ sdot) {
    if (blockIdx.x < 7) {
        int t = blockIdx.x * 256 + threadIdx.x;
        if (t >= NT_) return;
        double s = 0.0;
        for (int k = 0; k < NF_; ++k) s += (double)st[t + k] * (double)stf[k];
        ft[t] = s;
    } else {
        __shared__ double red[256];
        int b = blockIdx.x - 7;
        double s = 0.0;
        for (int p = threadIdx.x; p < P_; p += 256)
            s += (double)sp[(size_t)b * P_ + p] * (double)sf[p];
        red[threadIdx.x] = s;
        __syncthreads();
        for (int off = 128; off > 0; off >>= 1) {
            if (threadIdx.x < off) red[threadIdx.x] += red[threadIdx.x + off];
            __syncthreads();
        }
        if (threadIdx.x == 0) sdot[b] = red[0];
    }
}

// ---------------- gensig[b,t] = sdot[b]*ft[t] + bias + coup[b,t], f64 ----------------
__global__ __launch_bounds__(256) void k_coup(const float* __restrict__ cc,
                                              const float* __restrict__ cf,
                                              const double* __restrict__ sdot,
                                              const double* __restrict__ ft,
                                              const float* __restrict__ bias,
                                              double* __restrict__ gensig) {
    __shared__ __align__(16) float  ccs[NC_ * 512];   // 32 KB
    __shared__ __align__(16) double cfs[NC_ * 256];   // 32 KB
    __shared__ double red[3][64][4];                  // 6 KB
    int b = blockIdx.y, t0 = blockIdx.x * 256;
    int tid = threadIdx.x, lane = tid & 63, wv = tid >> 6;

    for (int idx = tid; idx < NC_ * 128; idx += 256) {
        int c = idx >> 7, j4 = (idx & 127) * 4, src = t0 + j4;
        const float* p = cc + ((size_t)b * NC_ + c) * NB_ + src;
        float4 v;
        if (src + 3 < NB_) v = *(const float4*)p;
        else {
            v.x = (src     < NB_) ? p[0] : 0.f;
            v.y = (src + 1 < NB_) ? p[1] : 0.f;
            v.z = (src + 2 < NB_) ? p[2] : 0.f;
            v.w = (src + 3 < NB_) ? p[3] : 0.f;
        }
        *(float4*)&ccs[c * 512 + j4] = v;
    }
    for (int idx = tid; idx < NC_ * 256; idx += 256) {
        int c = idx >> 8, k = idx & 255;
        cfs[idx] = (k < NF_) ? (double)cf[c * NF_ + k] : 0.0;
    }
    __syncthreads();

    double a0 = 0, a1 = 0, a2 = 0, a3 = 0;
    int base = lane * 4;
    for (int c = wv; c < NC_; c += 4) {
        const float*  row  = &ccs[c * 512];
        const double* crow = &cfs[c * 256];
        float4 cur = *(const float4*)&row[base];
        for (int k4 = 0; k4 < 252; k4 += 4) {
            float4 nxt = *(const float4*)&row[base + k4 + 4];
            double e0 = cur.x, e1 = cur.y, e2 = cur.z, e3 = cur.w;
            double e4 = nxt.x, e5 = nxt.y, e6 = nxt.z;
            double c0 = crow[k4], c1 = crow[k4 + 1], c2 = crow[k4 + 2], c3 = crow[k4 + 3];
            a0 += e0 * c0 + e1 * c1 + e2 * c2 + e3 * c3;
            a1 += e1 * c0 + e2 * c1 + e3 * c2 + e4 * c3;
            a2 += e2 * c0 + e3 * c1 + e4 * c2 + e5 * c3;
            a3 += e3 * c0 + e4 * c1 + e5 * c2 + e6 * c3;
            cur = nxt;
        }
    }
    if (wv > 0) {
        red[wv - 1][lane][0] = a0; red[wv - 1][lane][1] = a1;
        red[wv - 1][lane][2] = a2; red[wv - 1][lane][3] = a3;
    }
    __syncthreads();
    if (wv == 0) {
        a0 += red[0][lane][0] + red[1][lane][0] + red[2][lane][0];
        a1 += red[0][lane][1] + red[1][lane][1] + red[2][lane][1];
        a2 += red[0][lane][2] + red[1][lane][2] + red[2][lane][2];
        a3 += red[0][lane][3] + red[1][lane][3] + red[2][lane][3];
        double gb = (double)bias[0];
        double sd = sdot[b];
        double accs[4] = {a0, a1, a2, a3};
        int tb = t0 + base;
        for (int i = 0; i < 4; ++i) {
            int t = tb + i;
            if (t < LS_) gensig[(size_t)b * LS_ + t] = sd * ft[t] + gb + accs[i];
        }
    }
}

// ---------------- scan: i8-MFMA far + speculative 8-variant near rounds ----
// Waves 0..3 (scan): one wave per 16 chains. Waves 4..7 (prep): logit producers.
// NEAR: block = 4 rounds x 4 steps. Lane l = 4*cn + j owns step 4e+j of chain
//   cn. Per round, each lane computes all 8 speculative sums
//   Xv = base + {0,T1} + {0,T2} + {0,T3}  (unknown in-round ages 1..3),
//   ballots all 8 compares vs thr into SGPR planes Bm[0..7], then a pure-SALU
//   XOR-mux cascade resolves the 4 spike bits. Bit position 4c+j of a mask =
//   (chain c, step 4e+j). Selector masks come from resolved-round masks by
//   64-bit shifts (column algebra; static per-j, masked by COLj). Ages 4..6
//   enter the base via cndmask-with-mask selects (A4/A5/A6, round-granular);
//   ages 7..15 via QL-snapshot xbcalc; ages >=16 (incl. all pre-block) via
//   the MFMA far term inside thr. One VALU->SALU transfer per ROUND (was per
//   step) - this is the serial-latency fix.
__global__ __launch_bounds__(512, 2) void k_scan(const double* __restrict__ gensig,
                                                 const float* __restrict__ u,
                                                 const float* __restrict__ iss,
                                                 const float* __restrict__ ff,
                                                 float* __restrict__ out) {
    __shared__ double farT_all[4][16 * 17];          // 8.5 KB (scan waves only)
    __shared__ double luring[2][4][4 * 64];          // 16 KB: [slot][scanwave][e*64+lane]
    int tid = threadIdx.x;
    int wv = tid >> 6, l = tid & 63;
    int swv = wv & 3;
    const bool isPrep = (wv >= 4);
    int gw = blockIdx.x * 4 + swv;
    int b = gw >> 3, rbase = (gw & 7) * 16;
    double* farT = &farT_all[swv][0];

    int lw = l & 15;
    int q  = l >> 4;
    int cn = l >> 2;
    int j  = l & 3;
    int jo = 16 + j;            // sbfe offset base: bit(16 + t - a) with t = 4e+j

    const unsigned long long COL0_ = 0x1111111111111111ull;
    const unsigned long long COL1_ = COL0_ << 1;
    const unsigned long long COL2_ = COL0_ << 2;
    const unsigned long long COL3_ = COL0_ << 3;
    const unsigned long long COL01_ = COL0_ | COL1_;

    const double* gs   = gensig + (size_t)b * LS_;
    const float*  up   = u + b * R_ + rbase + cn;
    float*        op   = out + ((size_t)(b * R_ + rbase + cn)) * NB_ + NF_;
    const float*  issb = iss + b * NF_;

    // scan-wave state
    unsigned long long W0 = 0, W1 = 0, W2 = 0, W3 = 0;
    v4i Bf[4][6];
    double T1d = 0, T2d = 0, T3d = 0, T4d = 0, T5d = 0, T6d = 0;
    double tp7 = 0, tp8 = 0, tp9 = 0, tp10 = 0, tp11 = 0, tp12 = 0, tp13 = 0, tp14 = 0;
    double tp15 = 0;
    double thr0 = 0, thr1 = 0, thr2 = 0, thr3 = 0;
    double gprep = 0.0;
    // prep-wave state
    float ur0 = 0.f, ur1 = 0.f, ur2 = 0.f, ur3 = 0.f;

    if (!isPrep) {
        // ---- iss -> out[.., 0:250] ----
        for (int idx = l; idx < 16 * NF_; idx += 64) {
            int c = idx / NF_, k = idx - c * NF_;
            out[((size_t)(b * R_ + rbase + c)) * NB_ + k] = issb[k];
        }
        // ---- window: bit k = spike(t0-250+k) ----
        for (int k = 0; k < NF_; ++k) {
            unsigned long long bit = (issb[k] > 0.5f) ? 1ull : 0ull;
            if      (k <  64) W0 |= bit << k;
            else if (k < 128) W1 |= bit << (k - 64);
            else if (k < 192) W2 |= bit << (k - 128);
            else              W3 |= bit << (k - 192);
        }
        // ---- B: F[k][n] = ff[k-n]; 6 signed base-256 digit planes @2^48 ----
        int Bword[4][6][4];
#pragma unroll
        for (int kc = 0; kc < 4; ++kc)
#pragma unroll
            for (int p = 0; p < 6; ++p)
#pragma unroll
                for (int w = 0; w < 4; ++w) Bword[kc][p][w] = 0;
#pragma unroll
        for (int kc = 0; kc < 4; ++kc) {
#pragma unroll
            for (int jj = 0; jj < 16; ++jj) {
                int k = kc * 64 + q * 16 + jj;
                int idx = k - lw;
                long long v = 0;
                if (idx >= 0 && idx < NF_)
                    v = __double2ll_rn((double)ff[idx] * 281474976710656.0);   // * 2^48
#pragma unroll
                for (int p = 0; p < 6; ++p) {
                    int d = (int)((v + 128) & 255) - 128;
                    v = (v - (long long)d) >> 8;
                    Bword[kc][p][jj >> 2] |= (d & 255) << ((jj & 3) * 8);
                }
            }
        }
#pragma unroll
        for (int kc = 0; kc < 4; ++kc)
#pragma unroll
            for (int p = 0; p < 6; ++p) {
                v4i t; t.x = Bword[kc][p][0]; t.y = Bword[kc][p][1];
                t.z = Bword[kc][p][2]; t.w = Bword[kc][p][3];
                Bf[kc][p] = t;
            }
        // near taps, f64: age a -> ff[250-a]
        T1d  = (double)ff[249]; T2d  = (double)ff[248]; T3d  = (double)ff[247];
        T4d  = (double)ff[246]; T5d  = (double)ff[245]; T6d  = (double)ff[244];
        tp7  = (double)ff[243]; tp8  = (double)ff[242]; tp9  = (double)ff[241];
        tp10 = (double)ff[240]; tp11 = (double)ff[239]; tp12 = (double)ff[238];
        tp13 = (double)ff[237]; tp14 = (double)ff[236]; tp15 = (double)ff[235];
    } else {
        // ---- prep prologue: lu(0) -> slot0, lu(1) -> slot1, prefetch u(block 2) ----
        ur0 = up[(size_t)(0  + j) * BR_];
        ur1 = up[(size_t)(4  + j) * BR_];
        ur2 = up[(size_t)(8  + j) * BR_];
        ur3 = up[(size_t)(12 + j) * BR_];
        luring[0][swv][  0 + l] = logit_fast(ur0);
        luring[0][swv][ 64 + l] = logit_fast(ur1);
        luring[0][swv][128 + l] = logit_fast(ur2);
        luring[0][swv][192 + l] = logit_fast(ur3);
        ur0 = up[(size_t)(16 + j) * BR_];
        ur1 = up[(size_t)(20 + j) * BR_];
        ur2 = up[(size_t)(24 + j) * BR_];
        ur3 = up[(size_t)(28 + j) * BR_];
        luring[1][swv][  0 + l] = logit_fast(ur0);
        luring[1][swv][ 64 + l] = logit_fast(ur1);
        luring[1][swv][128 + l] = logit_fast(ur2);
        luring[1][swv][192 + l] = logit_fast(ur3);
        ur0 = up[(size_t)(32 + j) * BR_];
        ur1 = up[(size_t)(36 + j) * BR_];
        ur2 = up[(size_t)(40 + j) * BR_];
        ur3 = up[(size_t)(44 + j) * BR_];
    }

    // far phase: fb[chain=q*4+r][step=lw] = gp + sum_k W[k]*ff[k-lw]
    auto do_far = [&](double gp) {
        unsigned long long Sarr[4] = {W0, W1, W2, W3};
        v4i accm[6];
#pragma unroll
        for (int p = 0; p < 6; ++p) accm[p] = (v4i){0, 0, 0, 0};
#pragma unroll
        for (int kc = 0; kc < 4; ++kc) {
            unsigned f = (unsigned)((Sarr[kc] >> (q * 16)) & 0xFFFFull);
            v4i av;
            av.x = (int)((((f      ) & 0xFu) * 0x00204081u) & 0x01010101u);
            av.y = (int)((((f >>  4) & 0xFu) * 0x00204081u) & 0x01010101u);
            av.z = (int)((((f >>  8) & 0xFu) * 0x00204081u) & 0x01010101u);
            av.w = (int)((((f >> 12) & 0xFu) * 0x00204081u) & 0x01010101u);
#pragma unroll
            for (int p = 0; p < 6; ++p)
                accm[p] = __builtin_amdgcn_mfma_i32_16x16x64_i8(av, Bf[kc][p], accm[p], 0, 0, 0);
        }
#pragma unroll
        for (int r = 0; r < 4; ++r) {
            int lo = accm[0][r] + accm[1][r] * 256 + accm[2][r] * 65536;
            int hi = accm[3][r] + accm[4][r] * 256 + accm[5][r] * 65536;
            double fb = gp + (double)lo * 0x1p-48 + (double)hi * 0x1p-24;
            farT[(q * 4 + r) * 17 + lw] = fb;
        }
    };

    // ages 7..15 partial sum for round E (qsnap holds spike bits <= 4E-4 at 16+t)
    auto xbcalc = [&](int e4, unsigned qsnap) -> double {
        unsigned qs = qsnap >> e4;
        double x = (dand(tp7,  __builtin_amdgcn_sbfe((int)qs, jo - 7,  1)) +
                    dand(tp8,  __builtin_amdgcn_sbfe((int)qs, jo - 8,  1))) +
                   (dand(tp9,  __builtin_amdgcn_sbfe((int)qs, jo - 9,  1)) +
                    dand(tp10, __builtin_amdgcn_sbfe((int)qs, jo - 10, 1)));
        double y = (dand(tp11, __builtin_amdgcn_sbfe((int)qs, jo - 11, 1)) +
                    dand(tp12, __builtin_amdgcn_sbfe((int)qs, jo - 12, 1))) +
                   (dand(tp13, __builtin_amdgcn_sbfe((int)qs, jo - 13, 1)) +
                    dand(tp14, __builtin_amdgcn_sbfe((int)qs, jo - 14, 1)));
        return (x + y) + dand(tp15, __builtin_amdgcn_sbfe((int)qs, jo - 15, 1));
    };

    __syncthreads();   // A: prep's lu(0), lu(1) visible to scan waves

    if (!isPrep) {
        // ---- scan prologue: block 0 ----
        gprep = gs[lw];
        do_far(gprep);
        double lu0 = luring[0][swv][  0 + l];
        double lu1 = luring[0][swv][ 64 + l];
        double lu2 = luring[0][swv][128 + l];
        double lu3 = luring[0][swv][192 + l];
        __asm__ volatile("s_waitcnt lgkmcnt(0)" ::: "memory");
        thr0 = lu0 - farT[cn * 17 +  0 + j];
        thr1 = lu1 - farT[cn * 17 +  4 + j];
        thr2 = lu2 - farT[cn * 17 +  8 + j];
        thr3 = lu3 - farT[cn * 17 + 12 + j];
        { int tg = 16 + lw; if (tg > LS_ - 1) tg = LS_ - 1; gprep = gs[tg]; }
    }

    __syncthreads();   // B: scan's slot0 (lu(0)) reads done before prep overwrites it

// one 4-step round: E = round index (0..3), XB = ages-7..15 base, THR = round thr
#define ROUND(E, XB, THR) { \
    double d4 = dsel2(T4d, A4); \
    double d5 = dsel2(T5d, A5); \
    double d6 = dsel2(T6d, A6); \
    double xb0 = (XB) + ((d4 + d5) + d6); \
    double xb1 = xb0 + T1d; \
    double xc0 = xb0 + T2d, xc1 = xb1 + T2d; \
    double xd0 = xb0 + T3d, xd1 = xb1 + T3d, xd2 = xc0 + T3d, xd3 = xc1 + T3d; \
    unsigned long long Bm0 = __ballot(xb0 > (THR)); \
    unsigned long long Bm1 = __ballot(xb1 > (THR)); \
    unsigned long long Bm2 = __ballot(xc0 > (THR)); \
    unsigned long long Bm3 = __ballot(xc1 > (THR)); \
    unsigned long long Bm4 = __ballot(xd0 > (THR)); \
    unsigned long long Bm5 = __ballot(xd1 > (THR)); \
    unsigned long long Bm6 = __ballot(xd2 > (THR)); \
    unsigned long long Bm7 = __ballot(xd3 > (THR)); \
    unsigned long long a3p = P >> 1, a2p = P >> 2; \
    unsigned long long C0 = Bm0 ^ (a3p & (Bm4 ^ Bm0)); \
    unsigned long long C1 = Bm1 ^ (a3p & (Bm5 ^ Bm1)); \
    unsigned long long C2 = Bm2 ^ (a3p & (Bm6 ^ Bm2)); \
    unsigned long long C3 = Bm3 ^ (a3p & (Bm7 ^ Bm3)); \
    unsigned long long D0 = C0 ^ (a2p & (C2 ^ C0)); \
    unsigned long long D1 = C1 ^ (a2p & (C3 ^ C1)); \
    unsigned long long Dd = D1 ^ D0; \
    unsigned long long S = (D0 ^ ((P >> 3) & Dd)) & COL0_; \
    S |= (D0 ^ ((S << 1) & Dd)) & COL1_; \
    { unsigned long long a2s = S << 2; \
      unsigned long long D0b = C0 ^ (a2s & (C2 ^ C0)); \
      unsigned long long D1b = C1 ^ (a2s & (C3 ^ C1)); \
      S |= (D0b ^ ((S << 1) & (D1b ^ D0b))) & COL2_; } \
    { unsigned long long a3s = S << 3, a2s = S << 2; \
      unsigned long long C0c = Bm0 ^ (a3s & (Bm4 ^ Bm0)); \
      unsigned long long C1c = Bm1 ^ (a3s & (Bm5 ^ Bm1)); \
      unsigned long long C2c = Bm2 ^ (a3s & (Bm6 ^ Bm2)); \
      unsigned long long C3c = Bm3 ^ (a3s & (Bm7 ^ Bm3)); \
      unsigned long long D0c = C0c ^ (a2s & (C2c ^ C0c)); \
      unsigned long long D1c = C1c ^ (a2s & (C3c ^ C1c)); \
      S |= (D0c ^ ((S << 1) & (D1c ^ D0c))) & COL3_; } \
    unsigned long long mm; \
    mm = S & COL0_;        mm |= mm << 1; mm |= mm << 2; \
    QL = csel32(QL, QL | (1u << (16 + 4 * (E) + 0)), mm); \
    mm = (S >> 1) & COL0_; mm |= mm << 1; mm |= mm << 2; \
    QL = csel32(QL, QL | (1u << (16 + 4 * (E) + 1)), mm); \
    mm = (S >> 2) & COL0_; mm |= mm << 1; mm |= mm << 2; \
    QL = csel32(QL, QL | (1u << (16 + 4 * (E) + 2)), mm); \
    mm = (S >> 3) & COL0_; mm |= mm << 1; mm |= mm << 2; \
    QL = csel32(QL, QL | (1u << (16 + 4 * (E) + 3)), mm); \
    A4 = S; \
    A5 = ((S << 1) & ~COL0_) | ((P >> 3) & COL0_); \
    A6 = ((S << 2) & ~COL01_) | ((P >> 2) & COL01_); \
    P = S; \
}

    int blk = 0;
    for (int t0 = 0; t0 < LS_; t0 += H_, ++blk) {
        if (!isPrep) {
            // ---- NEAR: 4 speculative rounds of 4 steps ----
            unsigned QL = 0;
            unsigned long long P = 0, A4 = 0, A5 = 0, A6 = 0;
            double XB1, XB2, XB3;
            ROUND(0, 0.0, thr0)
            XB1 = xbcalc(4, QL);
            ROUND(1, XB1, thr1)
            XB2 = xbcalc(8, QL);
            ROUND(2, XB2, thr2)
            XB3 = xbcalc(12, QL);
            ROUND(3, XB3, thr3)
            unsigned q2 = QL >> 16;                    // bit i = spike(t0+i)

            // ---- store spikes ----
            int rem = LS_ - t0; if (rem > H_) rem = H_;
            int s0 = 4 * j;
            if (s0 + 3 < rem) {
                float4 o;
                o.x = (float)((q2 >> (s0    )) & 1u);
                o.y = (float)((q2 >> (s0 + 1)) & 1u);
                o.z = (float)((q2 >> (s0 + 2)) & 1u);
                o.w = (float)((q2 >> (s0 + 3)) & 1u);
                *(float4*)(op + t0 + s0) = o;
            } else {
#pragma unroll
                for (int e = 0; e < 4; ++e)
                    if (s0 + e < rem) op[t0 + s0 + e] = (float)((q2 >> (s0 + e)) & 1u);
            }

            if (t0 + H_ < LS_) {
                // lu(blk+1) was written by prep last iteration; issue reads early
                double lu0 = luring[(blk + 1) & 1][swv][  0 + l];
                double lu1 = luring[(blk + 1) & 1][swv][ 64 + l];
                double lu2 = luring[(blk + 1) & 1][swv][128 + l];
                double lu3 = luring[(blk + 1) & 1][swv][192 + l];

                // advance per-chain window with chain lw's new spikes
                int q2i = __builtin_amdgcn_ds_bpermute(lw << 4, (int)q2);
                unsigned long long q2n = (unsigned long long)(unsigned)q2i;
                W0 = (W0 >> 16) | (W1 << 48);
                W1 = (W1 >> 16) | (W2 << 48);
                W2 = (W2 >> 16) | (W3 << 48);
                W3 = (W3 >> 16) | (q2n << 42);

                do_far(gprep);                                  // block t0+16
                __asm__ volatile("s_waitcnt lgkmcnt(0)" ::: "memory");
                thr0 = lu0 - farT[cn * 17 +  0 + j];
                thr1 = lu1 - farT[cn * 17 +  4 + j];
                thr2 = lu2 - farT[cn * 17 +  8 + j];
                thr3 = lu3 - farT[cn * 17 + 12 + j];

                int tg = t0 + 32 + lw; if (tg > LS_ - 1) tg = LS_ - 1;
                gprep = gs[tg];
            }
        } else {
            // ---- prep: lu(blk+2) -> slot[blk&1]; prefetch u(block blk+3) ----
            if (blk <= NBLK_ - 3) {
                double lu0 = logit_fast(ur0), lu1 = logit_fast(ur1);
                double lu2 = logit_fast(ur2), lu3 = logit_fast(ur3);
                luring[blk & 1][swv][  0 + l] = lu0;
                luring[blk & 1][swv][ 64 + l] = lu1;
                luring[blk & 1][swv][128 + l] = lu2;
                luring[blk & 1][swv][192 + l] = lu3;
                if (blk <= NBLK_ - 4) {
                    int T = (blk + 3) * H_;
                    int t_;
                    t_ = T +  0 + j; if (t_ > LS_ - 1) t_ = LS_ - 1; ur0 = up[(size_t)t_ * BR_];
                    t_ = T +  4 + j; if (t_ > LS_ - 1) t_ = LS_ - 1; ur1 = up[(size_t)t_ * BR_];
                    t_ = T +  8 + j; if (t_ > LS_ - 1) t_ = LS_ - 1; ur2 = up[(size_t)t_ * BR_];
                    t_ = T + 12 + j; if (t_ > LS_ - 1) t_ = LS_ - 1; ur3 = up[(size_t)t_ * BR_];
                }
            }
        }
        __syncthreads();   // paces ring: write(t) | bar | read(t+1) | bar | overwrite(t+2)
    }
#undef ROUND
}

extern "C" void kernel_launch(void* const* d_in, const int* in_sizes, int n_in,
                              void* d_out, int out_size, void* d_ws, size_t ws_size,
                              hipStream_t stream) {
    const float* stim_spat = (const float*)d_in[0];   // (128,2048)
    const float* stim_time = (const float*)d_in[1];   // (2000,)
    const float* iss       = (const float*)d_in[2];   // (128,250)
    const float* cc        = (const float*)d_in[3];   // (128,16,2000)
    const float* sf        = (const float*)d_in[4];   // (2048,)
    const float* bias      = (const float*)d_in[5];   // (1,)
    const float* stf       = (const float*)d_in[6];   // (250,)
    const float* ff        = (const float*)d_in[7];   // (250,)
    const float* cf        = (const float*)d_in[8];   // (16,250)
    const float* u         = (const float*)d_in[9];   // (1750,128,128)
    (void)in_sizes; (void)n_in; (void)out_size; (void)ws_size;

    float* out = (float*)d_out;                       // (128,128,2000)

    double* ws     = (double*)d_ws;
    double* gensig = ws;                              // 128*1750 f64
    double* ft     = gensig + (size_t)B_ * LS_;       // 1751 f64
    double* sdot   = ft + NT_;                        // 128 f64

    k_pre  <<<135, 256, 0, stream>>>(stim_time, stf, stim_spat, sf, ft, sdot);
    k_coup <<<dim3(7, B_), 256, 0, stream>>>(cc, cf, sdot, ft, bias, gensig);
    k_scan <<<B_ * 2, 512, 0, stream>>>(gensig, u, iss, ff, out);
}